// Round 4
// baseline (2899.223 us; speedup 1.0000x reference)
//
#include <hip/hip_runtime.h>
#include <math.h>

typedef short bf16x8 __attribute__((ext_vector_type(8)));
typedef float f32x4 __attribute__((ext_vector_type(4)));

#define HH 8
#define NN 4096
#define DQK 320   // hi feature dim: [0..239] ip, [240..255] s, [256..303] dist_hi, [304..319] 0
#define DML 128   // mid/lo matrix: [0..47] dist_mid, [48..63] 0, [64..111] dist_lo, [112..127] 0
#define DV 272
#define BM 64
#define BN 32
#define NWAVE 4
#define MW 16
#define KT_LD 312 // 624B row stride = 156 dw == 28 mod 32 -> 2-way reads, no swizzle needed
#define VT_LD 40  // 80B stride = 20 dw -> 2-way reads

__device__ __forceinline__ unsigned short f2bf(float f) {
    unsigned int u = __float_as_uint(f);
    u = (u + 0x7fffu + ((u >> 16) & 1u)) >> 16;   // RNE
    return (unsigned short)u;
}
__device__ __forceinline__ float bf2f(unsigned short h) {
    return __uint_as_float(((unsigned int)h) << 16);
}

// ---- stage 1a: build split-precision bf16 feature matrices ----
__global__ void feat_kernel(const float* __restrict__ mv,
                            const float* __restrict__ sv,
                            const float* __restrict__ basis,
                            float scale,
                            unsigned short* __restrict__ dhi,
                            unsigned short* __restrict__ dml)
{
    __shared__ float sb[150];
    int t = threadIdx.x;
    if (t < 150) sb[t] = basis[t];
    __syncthreads();
    int row = blockIdx.x * 32 + (t >> 3);   // (h*4096+n)
    int c = t & 7;
    const float* m = mv + (size_t)row * 256 + c * 32;
    float f[32];
    #pragma unroll
    for (int i = 0; i < 8; ++i) {
        float4 v = ((const float4*)m)[i];
        f[i*4+0] = v.x; f[i*4+1] = v.y; f[i*4+2] = v.z; f[i*4+3] = v.w;
    }
    unsigned short* d  = dhi + (size_t)row * DQK;
    unsigned short* ml = dml + (size_t)row * DML;
    #pragma unroll
    for (int j = 0; j < 30; ++j)
        d[c*30 + j] = f2bf(f[1+j] * scale);
    float nn = 1.0f / sqrtf(f[5]*f[5] + 0.001f);
    float tn[5];
    #pragma unroll
    for (int x = 0; x < 5; ++x) tn[x] = f[1+x] * nn;
    #pragma unroll
    for (int z = 0; z < 6; ++z) {
        float acc = 0.f;
        #pragma unroll
        for (int x = 0; x < 5; ++x) {
            #pragma unroll
            for (int y = 0; y < 5; ++y)
                acc = fmaf(sb[(x*5+y)*6 + z] * tn[x], tn[y], acc);
        }
        acc *= scale;
        unsigned short hi = f2bf(acc);
        float r1 = acc - bf2f(hi);
        unsigned short mi = f2bf(r1);
        float r2 = r1 - bf2f(mi);
        unsigned short lo = f2bf(r2);
        d[256 + c*6 + z] = hi;
        ml[c*6 + z]      = mi;
        ml[64 + c*6 + z] = lo;
    }
    if (c < 2) {
        #pragma unroll
        for (int i = 0; i < 8; ++i) {
            int si = c*8 + i;
            d[240 + si] = f2bf(sv[(size_t)row*16 + si] * scale);
        }
    } else if (c == 2) {
        #pragma unroll
        for (int i = 0; i < 8; ++i) d[304 + i] = 0;
    } else if (c == 3) {
        #pragma unroll
        for (int i = 0; i < 8; ++i) d[312 + i] = 0;
    } else if (c == 4) {
        #pragma unroll
        for (int i = 0; i < 8; ++i) ml[48 + i] = 0;
    } else if (c == 5) {
        #pragma unroll
        for (int i = 0; i < 8; ++i) ml[56 + i] = 0;
    } else if (c == 6) {
        #pragma unroll
        for (int i = 0; i < 8; ++i) ml[112 + i] = 0;
    } else {
        #pragma unroll
        for (int i = 0; i < 8; ++i) ml[120 + i] = 0;
    }
}

// ---- stage 1b: V -> transposed bf16 [8][272][4096] ----
__global__ void vtrans_kernel(const float* __restrict__ vmv,
                              const float* __restrict__ vs,
                              unsigned short* __restrict__ dst)
{
    __shared__ unsigned short tile[64][DV];
    int blk = blockIdx.x;
    int h = blk >> 6;
    int n0 = (blk & 63) << 6;
    int t = threadIdx.x;
    #pragma unroll
    for (int it = 0; it < 16; ++it) {
        int v = t + it*256;
        int r = v >> 6;
        int sg = v & 63;
        float4 x = *(const float4*)(vmv + ((size_t)(h*NN + n0 + r))*256 + sg*4);
        tile[r][sg*4+0] = f2bf(x.x);
        tile[r][sg*4+1] = f2bf(x.y);
        tile[r][sg*4+2] = f2bf(x.z);
        tile[r][sg*4+3] = f2bf(x.w);
    }
    #pragma unroll
    for (int it = 0; it < 4; ++it) {
        int v = t + it*256;
        int r = v >> 4;
        int si = v & 15;
        tile[r][256 + si] = f2bf(vs[((size_t)(h*NN + n0 + r))*16 + si]);
    }
    __syncthreads();
    #pragma unroll
    for (int it = 0; it < 17; ++it) {      // 272 rows * 16 segs = 4352 = 17*256
        int v = t + it*256;
        int dd = v >> 4;
        int sg = v & 15;
        ushort4 o;
        o.x = tile[sg*4+0][dd];
        o.y = tile[sg*4+1][dd];
        o.z = tile[sg*4+2][dd];
        o.w = tile[sg*4+3][dd];
        *(ushort4*)(dst + ((size_t)(h*DV + dd))*NN + n0 + sg*4) = o;
    }
}

// ---- stage 2: flash attention, BM=64/BN=32, 3 blocks/CU, T14 async staging ----
__global__ __launch_bounds__(256, 3)
void attn_kernel(const unsigned short* __restrict__ Qf,
                 const unsigned short* __restrict__ Kf,
                 const unsigned short* __restrict__ Qml,
                 const unsigned short* __restrict__ Kml,
                 const unsigned short* __restrict__ Vt,
                 float* __restrict__ out)
{
    // 54,016 B total -> 3 blocks/CU
    __shared__ __align__(16) unsigned short kt_s[BN * KT_LD];          // 19968 B
    __shared__ __align__(16) unsigned short kml_s[BN * 128];           //  8192 B, chunk-swizzled
    __shared__ __align__(16) unsigned short vt_s[DV * VT_LD];          // 21760 B
    __shared__ __align__(16) unsigned short pb_s[NWAVE * MW * 32];     //  4096 B, chunk-swizzled

    int blk = blockIdx.x;
    // XCD swizzle: grid=512 (8|512) -> bijective; XCD x gets head x.
    int sbk = ((blk & 7) << 6) | (blk >> 3);
    int h = sbk >> 6;
    int q0 = (sbk & 63) * BM;
    int tid = threadIdx.x;
    int w = tid >> 6;
    int lane = tid & 63;
    int l15 = lane & 15;
    int l4 = lane >> 4;
    int l7 = l15 & 7;

    // Q fragments in registers (wave owns 16 q-rows)
    const unsigned short* qb = Qf + ((size_t)h*NN + q0 + w*MW + l15) * DQK + l4*8;
    const unsigned short* qm = Qml + ((size_t)h*NN + q0 + w*MW + l15) * DML + l4*8;
    bf16x8 qhi[10], qmid[2], qlo[2];
    #pragma unroll
    for (int ks = 0; ks < 10; ++ks)
        qhi[ks] = *(const bf16x8*)(qb + ks*32);
    #pragma unroll
    for (int ks = 0; ks < 2; ++ks) {
        qmid[ks] = *(const bf16x8*)(qm + ks*32);
        qlo[ks]  = *(const bf16x8*)(qm + 64 + ks*32);
    }

    f32x4 zero = {0.f, 0.f, 0.f, 0.f};
    f32x4 oacc[17];
    #pragma unroll
    for (int ct = 0; ct < 17; ++ct)
        oacc[ct] = zero;
    float mrow[4], lrow[4];
    #pragma unroll
    for (int j = 0; j < 4; ++j) { mrow[j] = -__builtin_inff(); lrow[j] = 0.f; }

    const unsigned short* kh  = Kf  + (size_t)h*NN*DQK;
    const unsigned short* kmh = Kml + (size_t)h*NN*DML;
    const unsigned short* vh  = Vt  + (size_t)h*DV*NN;

    bf16x8 st[12];   // T14 staging registers (48 VGPRs)

#define ISSUE(KT0) do {                                                          \
    const unsigned short* kb = kh + (size_t)(KT0)*DQK;                           \
    _Pragma("unroll")                                                            \
    for (int it = 0; it < 5; ++it) {                                             \
        int v = tid + it*256;                                                    \
        if (it < 4 || v < 1248) {                                                \
            int r = v / 39, c = v - r*39;                                        \
            st[it] = *(const bf16x8*)(kb + (size_t)r*DQK + c*8);                 \
        }                                                                        \
    }                                                                            \
    const unsigned short* mb = kmh + (size_t)(KT0)*DML;                          \
    _Pragma("unroll")                                                            \
    for (int it = 0; it < 2; ++it) {                                             \
        int v = tid + it*256;                                                    \
        int r = v >> 4, c = v & 15;                                              \
        st[5+it] = *(const bf16x8*)(mb + (size_t)r*DML + c*8);                   \
    }                                                                            \
    _Pragma("unroll")                                                            \
    for (int it = 0; it < 5; ++it) {                                             \
        int v = tid + it*256;                                                    \
        if (it < 4 || v < 1088) {                                                \
            int r = v >> 2, c = v & 3;                                           \
            st[7+it] = *(const bf16x8*)(vh + (size_t)r*NN + (KT0) + c*8);        \
        }                                                                        \
    }                                                                            \
} while (0)

#define WRITE() do {                                                             \
    _Pragma("unroll")                                                            \
    for (int it = 0; it < 5; ++it) {                                             \
        int v = tid + it*256;                                                    \
        if (it < 4 || v < 1248) {                                                \
            int r = v / 39, c = v - r*39;                                        \
            *(bf16x8*)&kt_s[r*KT_LD + c*8] = st[it];                             \
        }                                                                        \
    }                                                                            \
    _Pragma("unroll")                                                            \
    for (int it = 0; it < 2; ++it) {                                             \
        int v = tid + it*256;                                                    \
        int r = v >> 4, c = v & 15;                                              \
        *(bf16x8*)&kml_s[r*128 + ((c ^ (r & 7)) << 3)] = st[5+it];               \
    }                                                                            \
    _Pragma("unroll")                                                            \
    for (int it = 0; it < 5; ++it) {                                             \
        int v = tid + it*256;                                                    \
        if (it < 4 || v < 1088) {                                                \
            int r = v >> 2, c = v & 3;                                           \
            *(bf16x8*)&vt_s[r*VT_LD + c*8] = st[7+it];                           \
        }                                                                        \
    }                                                                            \
} while (0)

    ISSUE(0);

    for (int kt0 = 0; kt0 < NN; kt0 += BN) {
        __syncthreads();              // all waves done reading previous tile
        WRITE();                      // (compiler inserts vmcnt wait before ds_write)
        __syncthreads();              // tile visible
        if (kt0 + BN < NN) ISSUE(kt0 + BN);   // next tile's loads fly during compute

        f32x4 sacc[2];
        sacc[0] = zero; sacc[1] = zero;

        // ip + s dims (0..255): single bf16 pass
        __builtin_amdgcn_s_setprio(1);
        #pragma unroll
        for (int ks = 0; ks < 8; ++ks) {
            bf16x8 b0 = *(const bf16x8*)&kt_s[(l15)*KT_LD + ks*32 + l4*8];
            bf16x8 b1 = *(const bf16x8*)&kt_s[(16 + l15)*KT_LD + ks*32 + l4*8];
            sacc[0] = __builtin_amdgcn_mfma_f32_16x16x32_bf16(qhi[ks], b0, sacc[0], 0, 0, 0);
            sacc[1] = __builtin_amdgcn_mfma_f32_16x16x32_bf16(qhi[ks], b1, sacc[1], 0, 0, 0);
        }
        // dist dims (hi 256..311, 3-term split): hh, hm, mh, hl, lh, mm
        #pragma unroll
        for (int ks2 = 0; ks2 < 2; ++ks2) {
            #pragma unroll
            for (int ct = 0; ct < 2; ++ct) {
                int row = ct*16 + l15;
                bf16x8 bhi = *(const bf16x8*)&kt_s[row*KT_LD + 256 + ks2*32 + l4*8];
                bf16x8 bm  = *(const bf16x8*)&kml_s[row*128 + (((ks2*4 + l4) ^ l7) << 3)];
                bf16x8 bl  = *(const bf16x8*)&kml_s[row*128 + (((8 + ks2*4 + l4) ^ l7) << 3)];
                f32x4 a = sacc[ct];
                a = __builtin_amdgcn_mfma_f32_16x16x32_bf16(qhi[8+ks2], bhi, a, 0, 0, 0);
                a = __builtin_amdgcn_mfma_f32_16x16x32_bf16(qhi[8+ks2], bm,  a, 0, 0, 0);
                a = __builtin_amdgcn_mfma_f32_16x16x32_bf16(qmid[ks2],  bhi, a, 0, 0, 0);
                a = __builtin_amdgcn_mfma_f32_16x16x32_bf16(qhi[8+ks2], bl,  a, 0, 0, 0);
                a = __builtin_amdgcn_mfma_f32_16x16x32_bf16(qlo[ks2],   bhi, a, 0, 0, 0);
                a = __builtin_amdgcn_mfma_f32_16x16x32_bf16(qmid[ks2],  bm,  a, 0, 0, 0);
                sacc[ct] = a;
            }
        }
        __builtin_amdgcn_s_setprio(0);

        // online softmax; S row = l4*4 + j (within wave's 16), col = ct*16 + l15
        // l-sum is deferred: lrow[j] holds this lane's partial, reduced in epilogue.
        #pragma unroll
        for (int j = 0; j < 4; ++j) {
            float tm = fmaxf(sacc[0][j], sacc[1][j]);
            tm = fmaxf(tm, __shfl_xor(tm, 1, 64));
            tm = fmaxf(tm, __shfl_xor(tm, 2, 64));
            tm = fmaxf(tm, __shfl_xor(tm, 4, 64));
            tm = fmaxf(tm, __shfl_xor(tm, 8, 64));
            float mold = mrow[j];
            float mnew = fmaxf(mold, tm);
            mrow[j] = mnew;
            float p0 = __expf(sacc[0][j] - mnew);
            float p1 = __expf(sacc[1][j] - mnew);
            if (__all(mnew == mold)) {
                lrow[j] += p0 + p1;
            } else {
                float alpha = __expf(mold - mnew);   // 0 on first tile
                lrow[j] = lrow[j] * alpha + (p0 + p1);
                #pragma unroll
                for (int ct = 0; ct < 17; ++ct)
                    oacc[ct][j] *= alpha;
            }
            int prow = l4*4 + j;
            int swz = (prow >> 1) & 3;
            int base = (w*MW + prow) * 32;
            pb_s[base + ((((l15 >> 3)    ) ^ swz) << 3) + l7] = f2bf(p0);
            pb_s[base + ((((l15 >> 3) + 2) ^ swz) << 3) + l7] = f2bf(p1);
        }

        // PV: O += P(16x32) @ V(32x272)
        {
            bf16x8 pa = *(const bf16x8*)&pb_s[(w*MW + l15)*32 + ((l4 ^ ((l15 >> 1) & 3)) << 3)];
            __builtin_amdgcn_s_setprio(1);
            #pragma unroll
            for (int ct = 0; ct < 17; ++ct) {
                bf16x8 bv = *(const bf16x8*)&vt_s[(ct*16 + l15)*VT_LD + l4*8];
                oacc[ct] = __builtin_amdgcn_mfma_f32_16x16x32_bf16(pa, bv, oacc[ct], 0, 0, 0);
            }
            __builtin_amdgcn_s_setprio(0);
        }
    }

    // epilogue: reduce deferred l over the 16 lanes of each row, then scatter
    const size_t mv_total = (size_t)HH * NN * 256;
    #pragma unroll
    for (int j = 0; j < 4; ++j) {
        float l = lrow[j];
        l += __shfl_xor(l, 1, 64);
        l += __shfl_xor(l, 2, 64);
        l += __shfl_xor(l, 4, 64);
        l += __shfl_xor(l, 8, 64);
        float inv = 1.0f / l;
        int q = q0 + w*MW + l4*4 + j;
        float* po = out + ((size_t)h*NN + q) * 256 + l15;
        #pragma unroll
        for (int ct = 0; ct < 16; ++ct)
            po[ct*16] = oacc[ct][j] * inv;
        out[mv_total + ((size_t)h*NN + q)*16 + l15] = oacc[16][j] * inv;
    }
#undef ISSUE
#undef WRITE
}

extern "C" void kernel_launch(void* const* d_in, const int* in_sizes, int n_in,
                              void* d_out, int out_size, void* d_ws, size_t ws_size,
                              hipStream_t stream)
{
    const float* q_mv = (const float*)d_in[0];
    const float* k_mv = (const float*)d_in[1];
    const float* v_mv = (const float*)d_in[2];
    const float* q_s  = (const float*)d_in[3];
    const float* k_s  = (const float*)d_in[4];
    const float* v_s  = (const float*)d_in[5];
    const float* basis_q = (const float*)d_in[6];
    const float* basis_k = (const float*)d_in[7];
    float* out = (float*)d_out;

    unsigned short* qf  = (unsigned short*)d_ws;                  // [8][4096][320]
    unsigned short* kf  = qf  + (size_t)HH*NN*DQK;                // [8][4096][320]
    unsigned short* qml = kf  + (size_t)HH*NN*DQK;                // [8][4096][128]
    unsigned short* kml = qml + (size_t)HH*NN*DML;                // [8][4096][128]
    unsigned short* vt  = kml + (size_t)HH*NN*DML;                // [8][272][4096]
    // total ws use: 76,546,048 bytes

    const float qscale = 0.05735393346764042f;  // 1/sqrt(304); k-rescale is exactly 1

    feat_kernel<<<dim3(1024), dim3(256), 0, stream>>>(q_mv, q_s, basis_q, qscale, qf, qml);
    feat_kernel<<<dim3(1024), dim3(256), 0, stream>>>(k_mv, k_s, basis_k, 1.0f, kf, kml);
    vtrans_kernel<<<dim3(512), dim3(256), 0, stream>>>(v_mv, v_s, vt);
    attn_kernel<<<dim3(512), dim3(256), 0, stream>>>(qf, kf, qml, kml, vt, out);
}

// Round 5
// 2013.959 us; speedup vs baseline: 1.4396x; 1.4396x over previous
//
#include <hip/hip_runtime.h>
#include <math.h>

typedef short bf16x8 __attribute__((ext_vector_type(8)));
typedef float f32x4 __attribute__((ext_vector_type(4)));

#define HH 8
#define NN 4096
#define DQK 320   // hi feature dim (seg-swizzled in global): logical [0..239] ip, [240..255] s, [256..303] dist_hi, [304..319] 0
#define DML 128   // mid/lo (seg-swizzled): [0..47] mid, [48..63] 0, [64..111] lo, [112..127] 0
#define DV 272
#define BM 64
#define BN 32
#define NWAVE 4
#define MW 16

typedef const __attribute__((address_space(1))) unsigned int* gp_t;
typedef __attribute__((address_space(3))) unsigned int* lp_t;
__device__ __forceinline__ void gload16(const void* g, void* l) {
    __builtin_amdgcn_global_load_lds((gp_t)g, (lp_t)l, 16, 0, 0);
}

__device__ __forceinline__ unsigned short f2bf(float f) {
    unsigned int u = __float_as_uint(f);
    u = (u + 0x7fffu + ((u >> 16) & 1u)) >> 16;   // RNE
    return (unsigned short)u;
}
__device__ __forceinline__ float bf2f(unsigned short h) {
    return __uint_as_float(((unsigned int)h) << 16);
}

// ---- stage 1a: build split-precision bf16 feature matrices (seg-swizzled) ----
// physical seg = logical seg XOR (row&7)  (seg = 8 ush = 16 B)
__global__ void feat_kernel(const float* __restrict__ mv,
                            const float* __restrict__ sv,
                            const float* __restrict__ basis,
                            float scale,
                            unsigned short* __restrict__ dhi,
                            unsigned short* __restrict__ dml)
{
    __shared__ float sb[150];
    int t = threadIdx.x;
    if (t < 150) sb[t] = basis[t];
    __syncthreads();
    int row = blockIdx.x * 32 + (t >> 3);   // (h*4096+n)
    int c = t & 7;
    int rw7 = row & 7;
#define SWH(col) ((((((col) >> 3)) ^ rw7) << 3) | ((col) & 7))
    const float* m = mv + (size_t)row * 256 + c * 32;
    float f[32];
    #pragma unroll
    for (int i = 0; i < 8; ++i) {
        float4 v = ((const float4*)m)[i];
        f[i*4+0] = v.x; f[i*4+1] = v.y; f[i*4+2] = v.z; f[i*4+3] = v.w;
    }
    unsigned short* d  = dhi + (size_t)row * DQK;
    unsigned short* ml = dml + (size_t)row * DML;
    #pragma unroll
    for (int j = 0; j < 30; ++j)
        d[SWH(c*30 + j)] = f2bf(f[1+j] * scale);
    float nn = 1.0f / sqrtf(f[5]*f[5] + 0.001f);
    float tn[5];
    #pragma unroll
    for (int x = 0; x < 5; ++x) tn[x] = f[1+x] * nn;
    #pragma unroll
    for (int z = 0; z < 6; ++z) {
        float acc = 0.f;
        #pragma unroll
        for (int x = 0; x < 5; ++x) {
            #pragma unroll
            for (int y = 0; y < 5; ++y)
                acc = fmaf(sb[(x*5+y)*6 + z] * tn[x], tn[y], acc);
        }
        acc *= scale;
        unsigned short hi = f2bf(acc);
        float r1 = acc - bf2f(hi);
        unsigned short mi = f2bf(r1);
        float r2 = r1 - bf2f(mi);
        unsigned short lo = f2bf(r2);
        d[SWH(256 + c*6 + z)] = hi;
        ml[SWH(c*6 + z)]      = mi;
        ml[SWH(64 + c*6 + z)] = lo;
    }
    if (c < 2) {
        #pragma unroll
        for (int i = 0; i < 8; ++i) {
            int si = c*8 + i;
            d[SWH(240 + si)] = f2bf(sv[(size_t)row*16 + si] * scale);
        }
    } else if (c == 2) {
        #pragma unroll
        for (int i = 0; i < 8; ++i) d[SWH(304 + i)] = 0;
    } else if (c == 3) {
        #pragma unroll
        for (int i = 0; i < 8; ++i) d[SWH(312 + i)] = 0;
    } else if (c == 4) {
        #pragma unroll
        for (int i = 0; i < 8; ++i) ml[SWH(48 + i)] = 0;
    } else if (c == 5) {
        #pragma unroll
        for (int i = 0; i < 8; ++i) ml[SWH(56 + i)] = 0;
    } else if (c == 6) {
        #pragma unroll
        for (int i = 0; i < 8; ++i) ml[SWH(112 + i)] = 0;
    } else {
        #pragma unroll
        for (int i = 0; i < 8; ++i) ml[SWH(120 + i)] = 0;
    }
#undef SWH
}

// ---- stage 1b: V -> transposed bf16 [8][272][4096] (plain layout) ----
__global__ void vtrans_kernel(const float* __restrict__ vmv,
                              const float* __restrict__ vs,
                              unsigned short* __restrict__ dst)
{
    __shared__ unsigned short tile[64][DV];
    int blk = blockIdx.x;
    int h = blk >> 6;
    int n0 = (blk & 63) << 6;
    int t = threadIdx.x;
    #pragma unroll
    for (int it = 0; it < 16; ++it) {
        int v = t + it*256;
        int r = v >> 6;
        int sg = v & 63;
        float4 x = *(const float4*)(vmv + ((size_t)(h*NN + n0 + r))*256 + sg*4);
        tile[r][sg*4+0] = f2bf(x.x);
        tile[r][sg*4+1] = f2bf(x.y);
        tile[r][sg*4+2] = f2bf(x.z);
        tile[r][sg*4+3] = f2bf(x.w);
    }
    #pragma unroll
    for (int it = 0; it < 4; ++it) {
        int v = t + it*256;
        int r = v >> 4;
        int si = v & 15;
        tile[r][256 + si] = f2bf(vs[((size_t)(h*NN + n0 + r))*16 + si]);
    }
    __syncthreads();
    #pragma unroll
    for (int it = 0; it < 17; ++it) {      // 272 rows * 16 segs = 4352 = 17*256
        int v = t + it*256;
        int dd = v >> 4;
        int sg = v & 15;
        ushort4 o;
        o.x = tile[sg*4+0][dd];
        o.y = tile[sg*4+1][dd];
        o.z = tile[sg*4+2][dd];
        o.w = tile[sg*4+3][dd];
        *(ushort4*)(dst + ((size_t)(h*DV + dd))*NN + n0 + sg*4) = o;
    }
}

// ---- stage 2: flash attention, BM=64/BN=32, 3 blocks/CU, DMA staging ----
__global__ __launch_bounds__(256, 3)
void attn_kernel(const unsigned short* __restrict__ Qf,
                 const unsigned short* __restrict__ Kf,
                 const unsigned short* __restrict__ Qml,
                 const unsigned short* __restrict__ Kml,
                 const unsigned short* __restrict__ Vt,
                 float* __restrict__ out)
{
    // 50,176 B total -> 3 blocks/CU
    __shared__ __align__(16) unsigned short kt_s[32 * 320];        // 20480 B, seg-swizzled rows
    __shared__ __align__(16) unsigned short kml_s[32 * 128];       //  8192 B, seg-swizzled rows
    __shared__ __align__(16) unsigned short vt_s[136 * 64];        // 17408 B, 2-row chunks, slot^ (chunk&7)
    __shared__ __align__(16) unsigned short pb_s[NWAVE * MW * 32]; //  4096 B, swizzled

    int blk = blockIdx.x;
    // XCD swizzle: grid=512 (8|512) -> bijective; XCD x gets head x.
    int sbk = ((blk & 7) << 6) | (blk >> 3);
    int h = sbk >> 6;
    int q0 = (sbk & 63) * BM;
    int tid = threadIdx.x;
    int w = tid >> 6;
    int lane = tid & 63;
    int l15 = lane & 15;
    int l4 = lane >> 4;
    int l7 = l15 & 7;
    int l7h = l7 >> 2;            // flips low bit of seg-group index
    int c_l = l4 ^ (l7 & 3);      // swizzled within-group slot
    int wb = (tid & 192) * 8;     // wave LDS base (ush), uniform per wave

    // Q fragments in registers (global is seg-swizzled; row&7 == l7)
    const unsigned short* qrow = Qf + (size_t)(h*NN + q0 + w*MW + l15) * DQK;
    const unsigned short* qmrow = Qml + (size_t)(h*NN + q0 + w*MW + l15) * DML;
    bf16x8 qhi[10], qmid[2], qlo[2];
    #pragma unroll
    for (int ks = 0; ks < 10; ++ks)
        qhi[ks] = *(const bf16x8*)(qrow + (((ks ^ l7h) << 2) + c_l) * 8);
    #pragma unroll
    for (int ks = 0; ks < 2; ++ks) {
        qmid[ks] = *(const bf16x8*)(qmrow + (((ks ^ l7h) << 2) + c_l) * 8);
        qlo[ks]  = *(const bf16x8*)(qmrow + 64 + (((ks ^ l7h) << 2) + c_l) * 8);
    }

    // per-lane LDS read bases (bytes)
    int kbase[10];
    #pragma unroll
    for (int ks = 0; ks < 10; ++ks)
        kbase[ks] = (l15*320 + (((ks ^ l7h) << 2) + c_l) * 8) * 2;
    int mlb[2];
    #pragma unroll
    for (int ks = 0; ks < 2; ++ks)
        mlb[ks] = (l15*128 + (((ks ^ l7h) << 2) + c_l) * 8) * 2;
    int vbase = ((l15 >> 1)*64 + ((((l15 & 1) << 2) | l4) ^ (l15 >> 1)) * 8) * 2;
    int pbr = ((w*MW + l15)*32 + ((l4 ^ ((l15 >> 1) & 3)) << 3)) * 2;

    // DMA source offsets (ush), computed once
    int ktoff[5], mloff[2], vtoff[5];
    #pragma unroll
    for (int it = 0; it < 5; ++it) {
        int idx = tid + it*256;
        int r = idx / 40, c = idx - r*40;
        ktoff[it] = r*DQK + c*8;
    }
    #pragma unroll
    for (int it = 0; it < 2; ++it) {
        int idx = tid + it*256;
        mloff[it] = (idx >> 4)*DML + (idx & 15)*8;
    }
    #pragma unroll
    for (int it = 0; it < 5; ++it) {
        int idx = tid + it*256;
        int ch = idx >> 3, ws = idx & 7;
        int lw = ws ^ (ch & 7);
        vtoff[it] = (ch*2 + (lw >> 2))*NN + (lw & 3)*8;
    }

    f32x4 zero = {0.f, 0.f, 0.f, 0.f};
    f32x4 oacc[17];
    #pragma unroll
    for (int ct = 0; ct < 17; ++ct)
        oacc[ct] = zero;
    float mrow[4], lrow[4];
    #pragma unroll
    for (int j = 0; j < 4; ++j) { mrow[j] = -__builtin_inff(); lrow[j] = 0.f; }

    const unsigned short* kh  = Kf  + (size_t)h*NN*DQK;
    const unsigned short* kmh = Kml + (size_t)h*NN*DML;
    const unsigned short* vh  = Vt  + (size_t)h*DV*NN;

    for (int kt0 = 0; kt0 < NN; kt0 += BN) {
        // ---- async DMA staging (LDS is free: end-of-loop barrier passed) ----
        {
            const unsigned short* ksrc = kh + (size_t)kt0*DQK;
            #pragma unroll
            for (int it = 0; it < 5; ++it)
                gload16(ksrc + ktoff[it], kt_s + it*2048 + wb);
            const unsigned short* msrc = kmh + (size_t)kt0*DML;
            #pragma unroll
            for (int it = 0; it < 2; ++it)
                gload16(msrc + mloff[it], kml_s + it*2048 + wb);
            const unsigned short* vsrc = vh + kt0;
            #pragma unroll
            for (int it = 0; it < 4; ++it)
                gload16(vsrc + vtoff[it], vt_s + it*2048 + wb);
            if (tid < 64)
                gload16(vsrc + vtoff[4], vt_s + 4*2048 + wb);
        }
        __syncthreads();   // vmcnt(0) drain + barrier: tile visible to all

        f32x4 sacc[2];
        sacc[0] = zero; sacc[1] = zero;

        // ip + s dims (logical 0..255): single bf16 pass
        __builtin_amdgcn_s_setprio(1);
        #pragma unroll
        for (int ks = 0; ks < 8; ++ks) {
            bf16x8 b0 = *(const bf16x8*)((const char*)kt_s + kbase[ks]);
            bf16x8 b1 = *(const bf16x8*)((const char*)kt_s + kbase[ks] + 10240);
            sacc[0] = __builtin_amdgcn_mfma_f32_16x16x32_bf16(qhi[ks], b0, sacc[0], 0, 0, 0);
            sacc[1] = __builtin_amdgcn_mfma_f32_16x16x32_bf16(qhi[ks], b1, sacc[1], 0, 0, 0);
        }
        // dist dims (logical 256..319, 3-term split): hh, hm, mh, hl, lh, mm
        #pragma unroll
        for (int ks2 = 0; ks2 < 2; ++ks2) {
            #pragma unroll
            for (int ct = 0; ct < 2; ++ct) {
                bf16x8 bhi = *(const bf16x8*)((const char*)kt_s + kbase[8+ks2] + ct*10240);
                bf16x8 bm  = *(const bf16x8*)((const char*)kml_s + mlb[ks2] + ct*4096);
                bf16x8 bl  = *(const bf16x8*)((const char*)kml_s + mlb[ks2] + ct*4096 + 128);
                f32x4 a = sacc[ct];
                a = __builtin_amdgcn_mfma_f32_16x16x32_bf16(qhi[8+ks2], bhi, a, 0, 0, 0);
                a = __builtin_amdgcn_mfma_f32_16x16x32_bf16(qhi[8+ks2], bm,  a, 0, 0, 0);
                a = __builtin_amdgcn_mfma_f32_16x16x32_bf16(qmid[ks2],  bhi, a, 0, 0, 0);
                a = __builtin_amdgcn_mfma_f32_16x16x32_bf16(qhi[8+ks2], bl,  a, 0, 0, 0);
                a = __builtin_amdgcn_mfma_f32_16x16x32_bf16(qlo[ks2],   bhi, a, 0, 0, 0);
                a = __builtin_amdgcn_mfma_f32_16x16x32_bf16(qmid[ks2],  bm,  a, 0, 0, 0);
                sacc[ct] = a;
            }
        }
        __builtin_amdgcn_s_setprio(0);

        // online softmax; S row = l4*4 + j (wave's 16 rows), col = ct*16 + l15
        // l-sum deferred: lrow[j] holds this lane's partial, reduced in epilogue.
        #pragma unroll
        for (int j = 0; j < 4; ++j) {
            float tm = fmaxf(sacc[0][j], sacc[1][j]);
            tm = fmaxf(tm, __shfl_xor(tm, 1, 64));
            tm = fmaxf(tm, __shfl_xor(tm, 2, 64));
            tm = fmaxf(tm, __shfl_xor(tm, 4, 64));
            tm = fmaxf(tm, __shfl_xor(tm, 8, 64));
            float mold = mrow[j];
            float mnew = fmaxf(mold, tm);
            mrow[j] = mnew;
            float p0 = __expf(sacc[0][j] - mnew);
            float p1 = __expf(sacc[1][j] - mnew);
            if (__all(mnew == mold)) {
                lrow[j] += p0 + p1;
            } else {
                float alpha = __expf(mold - mnew);   // 0 on first tile
                lrow[j] = lrow[j] * alpha + (p0 + p1);
                #pragma unroll
                for (int ct = 0; ct < 17; ++ct)
                    oacc[ct][j] *= alpha;
            }
            int prow = l4*4 + j;
            int swz = (prow >> 1) & 3;
            int base = (w*MW + prow) * 32;
            pb_s[base + ((((l15 >> 3)    ) ^ swz) << 3) + l7] = f2bf(p0);
            pb_s[base + ((((l15 >> 3) + 2) ^ swz) << 3) + l7] = f2bf(p1);
        }

        // PV: O += P(16x32) @ V(32x272)
        {
            bf16x8 pa = *(const bf16x8*)((const char*)pb_s + pbr);
            __builtin_amdgcn_s_setprio(1);
            #pragma unroll
            for (int ct = 0; ct < 17; ++ct) {
                bf16x8 bv = *(const bf16x8*)((const char*)vt_s + vbase + ct*1024);
                oacc[ct] = __builtin_amdgcn_mfma_f32_16x16x32_bf16(pa, bv, oacc[ct], 0, 0, 0);
            }
            __builtin_amdgcn_s_setprio(0);
        }
        __syncthreads();   // all waves done reading; next iter's DMA may write
    }

    // epilogue: reduce deferred l over the 16 lanes of each row, then scatter
    const size_t mv_total = (size_t)HH * NN * 256;
    #pragma unroll
    for (int j = 0; j < 4; ++j) {
        float l = lrow[j];
        l += __shfl_xor(l, 1, 64);
        l += __shfl_xor(l, 2, 64);
        l += __shfl_xor(l, 4, 64);
        l += __shfl_xor(l, 8, 64);
        float inv = 1.0f / l;
        int q = q0 + w*MW + l4*4 + j;
        float* po = out + ((size_t)h*NN + q) * 256 + l15;
        #pragma unroll
        for (int ct = 0; ct < 16; ++ct)
            po[ct*16] = oacc[ct][j] * inv;
        out[mv_total + ((size_t)h*NN + q)*16 + l15] = oacc[16][j] * inv;
    }
}

extern "C" void kernel_launch(void* const* d_in, const int* in_sizes, int n_in,
                              void* d_out, int out_size, void* d_ws, size_t ws_size,
                              hipStream_t stream)
{
    const float* q_mv = (const float*)d_in[0];
    const float* k_mv = (const float*)d_in[1];
    const float* v_mv = (const float*)d_in[2];
    const float* q_s  = (const float*)d_in[3];
    const float* k_s  = (const float*)d_in[4];
    const float* v_s  = (const float*)d_in[5];
    const float* basis_q = (const float*)d_in[6];
    const float* basis_k = (const float*)d_in[7];
    float* out = (float*)d_out;

    unsigned short* qf  = (unsigned short*)d_ws;                  // [8][4096][320]
    unsigned short* kf  = qf  + (size_t)HH*NN*DQK;                // [8][4096][320]
    unsigned short* qml = kf  + (size_t)HH*NN*DQK;                // [8][4096][128]
    unsigned short* kml = qml + (size_t)HH*NN*DML;                // [8][4096][128]
    unsigned short* vt  = kml + (size_t)HH*NN*DML;                // [8][272][4096]
    // total ws use: 76,546,048 bytes

    const float qscale = 0.05735393346764042f;  // 1/sqrt(304); k-rescale is exactly 1

    feat_kernel<<<dim3(1024), dim3(256), 0, stream>>>(q_mv, q_s, basis_q, qscale, qf, qml);
    feat_kernel<<<dim3(1024), dim3(256), 0, stream>>>(k_mv, k_s, basis_k, 1.0f, kf, kml);
    vtrans_kernel<<<dim3(512), dim3(256), 0, stream>>>(v_mv, v_s, vt);
    attn_kernel<<<dim3(512), dim3(256), 0, stream>>>(qf, kf, qml, kml, vt, out);
}

// Round 6
// 802.482 us; speedup vs baseline: 3.6128x; 2.5097x over previous
//
#include <hip/hip_runtime.h>
#include <math.h>

typedef short bf16x8 __attribute__((ext_vector_type(8)));
typedef float f32x4 __attribute__((ext_vector_type(4)));

#define HH 8
#define NN 4096
#define DQK 320   // hi feature dim (seg-swizzled in global): logical [0..239] ip, [240..255] s, [256..303] dist_hi, [304..319] 0
#define DML 128   // mid/lo (seg-swizzled): [0..47] mid, [48..63] 0, [64..111] lo, [112..127] 0
#define DV 272
#define BM 64
#define BN 32
#define NWAVE 4
#define MW 16

typedef const __attribute__((address_space(1))) unsigned int* gp_t;
typedef __attribute__((address_space(3))) unsigned int* lp_t;
__device__ __forceinline__ void gload16(const void* g, void* l) {
    __builtin_amdgcn_global_load_lds((gp_t)g, (lp_t)l, 16, 0, 0);
}

__device__ __forceinline__ unsigned short f2bf(float f) {
    unsigned int u = __float_as_uint(f);
    u = (u + 0x7fffu + ((u >> 16) & 1u)) >> 16;   // RNE
    return (unsigned short)u;
}
__device__ __forceinline__ float bf2f(unsigned short h) {
    return __uint_as_float(((unsigned int)h) << 16);
}

// ---- stage 1a: build split-precision bf16 feature matrices (seg-swizzled) ----
// physical seg = logical seg XOR (row&7)  (seg = 8 ush = 16 B)
__global__ void feat_kernel(const float* __restrict__ mv,
                            const float* __restrict__ sv,
                            const float* __restrict__ basis,
                            float scale,
                            unsigned short* __restrict__ dhi,
                            unsigned short* __restrict__ dml)
{
    __shared__ float sb[150];
    int t = threadIdx.x;
    if (t < 150) sb[t] = basis[t];
    __syncthreads();
    int row = blockIdx.x * 32 + (t >> 3);   // (h*4096+n)
    int c = t & 7;
    int rw7 = row & 7;
#define SWH(col) ((((((col) >> 3)) ^ rw7) << 3) | ((col) & 7))
    const float* m = mv + (size_t)row * 256 + c * 32;
    float f[32];
    #pragma unroll
    for (int i = 0; i < 8; ++i) {
        float4 v = ((const float4*)m)[i];
        f[i*4+0] = v.x; f[i*4+1] = v.y; f[i*4+2] = v.z; f[i*4+3] = v.w;
    }
    unsigned short* d  = dhi + (size_t)row * DQK;
    unsigned short* ml = dml + (size_t)row * DML;
    #pragma unroll
    for (int j = 0; j < 30; ++j)
        d[SWH(c*30 + j)] = f2bf(f[1+j] * scale);
    float nn = 1.0f / sqrtf(f[5]*f[5] + 0.001f);
    float tn[5];
    #pragma unroll
    for (int x = 0; x < 5; ++x) tn[x] = f[1+x] * nn;
    #pragma unroll
    for (int z = 0; z < 6; ++z) {
        float acc = 0.f;
        #pragma unroll
        for (int x = 0; x < 5; ++x) {
            #pragma unroll
            for (int y = 0; y < 5; ++y)
                acc = fmaf(sb[(x*5+y)*6 + z] * tn[x], tn[y], acc);
        }
        acc *= scale;
        unsigned short hi = f2bf(acc);
        float r1 = acc - bf2f(hi);
        unsigned short mi = f2bf(r1);
        float r2 = r1 - bf2f(mi);
        unsigned short lo = f2bf(r2);
        d[SWH(256 + c*6 + z)] = hi;
        ml[SWH(c*6 + z)]      = mi;
        ml[SWH(64 + c*6 + z)] = lo;
    }
    if (c < 2) {
        #pragma unroll
        for (int i = 0; i < 8; ++i) {
            int si = c*8 + i;
            d[SWH(240 + si)] = f2bf(sv[(size_t)row*16 + si] * scale);
        }
    } else if (c == 2) {
        #pragma unroll
        for (int i = 0; i < 8; ++i) d[SWH(304 + i)] = 0;
    } else if (c == 3) {
        #pragma unroll
        for (int i = 0; i < 8; ++i) d[SWH(312 + i)] = 0;
    } else if (c == 4) {
        #pragma unroll
        for (int i = 0; i < 8; ++i) ml[SWH(48 + i)] = 0;
    } else if (c == 5) {
        #pragma unroll
        for (int i = 0; i < 8; ++i) ml[SWH(56 + i)] = 0;
    } else if (c == 6) {
        #pragma unroll
        for (int i = 0; i < 8; ++i) ml[SWH(112 + i)] = 0;
    } else {
        #pragma unroll
        for (int i = 0; i < 8; ++i) ml[SWH(120 + i)] = 0;
    }
#undef SWH
}

// ---- stage 1b: V -> transposed bf16 [8][272][4096] (plain layout) ----
__global__ void vtrans_kernel(const float* __restrict__ vmv,
                              const float* __restrict__ vs,
                              unsigned short* __restrict__ dst)
{
    __shared__ unsigned short tile[64][DV];
    int blk = blockIdx.x;
    int h = blk >> 6;
    int n0 = (blk & 63) << 6;
    int t = threadIdx.x;
    #pragma unroll
    for (int it = 0; it < 16; ++it) {
        int v = t + it*256;
        int r = v >> 6;
        int sg = v & 63;
        float4 x = *(const float4*)(vmv + ((size_t)(h*NN + n0 + r))*256 + sg*4);
        tile[r][sg*4+0] = f2bf(x.x);
        tile[r][sg*4+1] = f2bf(x.y);
        tile[r][sg*4+2] = f2bf(x.z);
        tile[r][sg*4+3] = f2bf(x.w);
    }
    #pragma unroll
    for (int it = 0; it < 4; ++it) {
        int v = t + it*256;
        int r = v >> 4;
        int si = v & 15;
        tile[r][256 + si] = f2bf(vs[((size_t)(h*NN + n0 + r))*16 + si]);
    }
    __syncthreads();
    #pragma unroll
    for (int it = 0; it < 17; ++it) {      // 272 rows * 16 segs = 4352 = 17*256
        int v = t + it*256;
        int dd = v >> 4;
        int sg = v & 15;
        ushort4 o;
        o.x = tile[sg*4+0][dd];
        o.y = tile[sg*4+1][dd];
        o.z = tile[sg*4+2][dd];
        o.w = tile[sg*4+3][dd];
        *(ushort4*)(dst + ((size_t)(h*DV + dd))*NN + n0 + sg*4) = o;
    }
}

// ---- stage 2: flash attention, BM=64/BN=32, 2 blocks/CU (VGPR cap 256 -> no spill), DMA staging ----
__global__ __launch_bounds__(256, 2)
void attn_kernel(const unsigned short* __restrict__ Qf,
                 const unsigned short* __restrict__ Kf,
                 const unsigned short* __restrict__ Qml,
                 const unsigned short* __restrict__ Kml,
                 const unsigned short* __restrict__ Vt,
                 float* __restrict__ out)
{
    // 50,176 B total
    __shared__ __align__(16) unsigned short kt_s[32 * 320];        // 20480 B, seg-swizzled rows
    __shared__ __align__(16) unsigned short kml_s[32 * 128];       //  8192 B, seg-swizzled rows
    __shared__ __align__(16) unsigned short vt_s[136 * 64];        // 17408 B, 2-row chunks, slot^ (chunk&7)
    __shared__ __align__(16) unsigned short pb_s[NWAVE * MW * 32]; //  4096 B, swizzled

    int blk = blockIdx.x;
    // XCD swizzle: grid=512 (8|512) -> bijective; XCD x gets head x.
    int sbk = ((blk & 7) << 6) | (blk >> 3);
    int h = sbk >> 6;
    int q0 = (sbk & 63) * BM;
    int tid = threadIdx.x;
    int w = tid >> 6;
    int lane = tid & 63;
    int l15 = lane & 15;
    int l4 = lane >> 4;
    int l7 = l15 & 7;
    int l7h = l7 >> 2;            // flips low bit of seg-group index
    int c_l = l4 ^ (l7 & 3);      // swizzled within-group slot
    int wb = (tid & 192) * 8;     // wave LDS base (ush), uniform per wave

    // Q fragments in registers (global is seg-swizzled; row&7 == l7)
    const unsigned short* qrow = Qf + (size_t)(h*NN + q0 + w*MW + l15) * DQK;
    const unsigned short* qmrow = Qml + (size_t)(h*NN + q0 + w*MW + l15) * DML;
    bf16x8 qhi[10], qmid[2], qlo[2];
    #pragma unroll
    for (int ks = 0; ks < 10; ++ks)
        qhi[ks] = *(const bf16x8*)(qrow + (((ks ^ l7h) << 2) + c_l) * 8);
    #pragma unroll
    for (int ks = 0; ks < 2; ++ks) {
        qmid[ks] = *(const bf16x8*)(qmrow + (((ks ^ l7h) << 2) + c_l) * 8);
        qlo[ks]  = *(const bf16x8*)(qmrow + 64 + (((ks ^ l7h) << 2) + c_l) * 8);
    }

    // per-lane LDS read bases (bytes)
    int kbase[10];
    #pragma unroll
    for (int ks = 0; ks < 10; ++ks)
        kbase[ks] = (l15*320 + (((ks ^ l7h) << 2) + c_l) * 8) * 2;
    int mlb[2];
    #pragma unroll
    for (int ks = 0; ks < 2; ++ks)
        mlb[ks] = (l15*128 + (((ks ^ l7h) << 2) + c_l) * 8) * 2;
    int vbase = ((l15 >> 1)*64 + ((((l15 & 1) << 2) | l4) ^ (l15 >> 1)) * 8) * 2;
    int pbr = ((w*MW + l15)*32 + ((l4 ^ ((l15 >> 1) & 3)) << 3)) * 2;

    // DMA source offsets (ush), computed once
    int ktoff[5], mloff[2], vtoff[5];
    #pragma unroll
    for (int it = 0; it < 5; ++it) {
        int idx = tid + it*256;
        int r = idx / 40, c = idx - r*40;
        ktoff[it] = r*DQK + c*8;
    }
    #pragma unroll
    for (int it = 0; it < 2; ++it) {
        int idx = tid + it*256;
        mloff[it] = (idx >> 4)*DML + (idx & 15)*8;
    }
    #pragma unroll
    for (int it = 0; it < 5; ++it) {
        int idx = tid + it*256;
        int ch = idx >> 3, ws = idx & 7;
        int lw = ws ^ (ch & 7);
        vtoff[it] = (ch*2 + (lw >> 2))*NN + (lw & 3)*8;
    }

    f32x4 zero = {0.f, 0.f, 0.f, 0.f};
    f32x4 oacc[17];
    #pragma unroll
    for (int ct = 0; ct < 17; ++ct)
        oacc[ct] = zero;
    float mrow[4], lrow[4];
    #pragma unroll
    for (int j = 0; j < 4; ++j) { mrow[j] = -__builtin_inff(); lrow[j] = 0.f; }

    const unsigned short* kh  = Kf  + (size_t)h*NN*DQK;
    const unsigned short* kmh = Kml + (size_t)h*NN*DML;
    const unsigned short* vh  = Vt  + (size_t)h*DV*NN;

    for (int kt0 = 0; kt0 < NN; kt0 += BN) {
        // ---- async DMA staging (LDS is free: end-of-loop barrier passed) ----
        {
            const unsigned short* ksrc = kh + (size_t)kt0*DQK;
            #pragma unroll
            for (int it = 0; it < 5; ++it)
                gload16(ksrc + ktoff[it], kt_s + it*2048 + wb);
            const unsigned short* msrc = kmh + (size_t)kt0*DML;
            #pragma unroll
            for (int it = 0; it < 2; ++it)
                gload16(msrc + mloff[it], kml_s + it*2048 + wb);
            const unsigned short* vsrc = vh + kt0;
            #pragma unroll
            for (int it = 0; it < 4; ++it)
                gload16(vsrc + vtoff[it], vt_s + it*2048 + wb);
            if (tid < 64)
                gload16(vsrc + vtoff[4], vt_s + 4*2048 + wb);
        }
        __syncthreads();   // vmcnt(0) drain + barrier: tile visible to all

        f32x4 sacc[2];
        sacc[0] = zero; sacc[1] = zero;

        // ip + s dims (logical 0..255): single bf16 pass
        __builtin_amdgcn_s_setprio(1);
        #pragma unroll
        for (int ks = 0; ks < 8; ++ks) {
            bf16x8 b0 = *(const bf16x8*)((const char*)kt_s + kbase[ks]);
            bf16x8 b1 = *(const bf16x8*)((const char*)kt_s + kbase[ks] + 10240);
            sacc[0] = __builtin_amdgcn_mfma_f32_16x16x32_bf16(qhi[ks], b0, sacc[0], 0, 0, 0);
            sacc[1] = __builtin_amdgcn_mfma_f32_16x16x32_bf16(qhi[ks], b1, sacc[1], 0, 0, 0);
        }
        // dist dims (logical 256..319, 3-term split): hh, hm, mh, hl, lh, mm
        #pragma unroll
        for (int ks2 = 0; ks2 < 2; ++ks2) {
            #pragma unroll
            for (int ct = 0; ct < 2; ++ct) {
                bf16x8 bhi = *(const bf16x8*)((const char*)kt_s + kbase[8+ks2] + ct*10240);
                bf16x8 bm  = *(const bf16x8*)((const char*)kml_s + mlb[ks2] + ct*4096);
                bf16x8 bl  = *(const bf16x8*)((const char*)kml_s + mlb[ks2] + ct*4096 + 128);
                f32x4 a = sacc[ct];
                a = __builtin_amdgcn_mfma_f32_16x16x32_bf16(qhi[8+ks2], bhi, a, 0, 0, 0);
                a = __builtin_amdgcn_mfma_f32_16x16x32_bf16(qhi[8+ks2], bm,  a, 0, 0, 0);
                a = __builtin_amdgcn_mfma_f32_16x16x32_bf16(qmid[ks2],  bhi, a, 0, 0, 0);
                a = __builtin_amdgcn_mfma_f32_16x16x32_bf16(qhi[8+ks2], bl,  a, 0, 0, 0);
                a = __builtin_amdgcn_mfma_f32_16x16x32_bf16(qlo[ks2],   bhi, a, 0, 0, 0);
                a = __builtin_amdgcn_mfma_f32_16x16x32_bf16(qmid[ks2],  bm,  a, 0, 0, 0);
                sacc[ct] = a;
            }
        }
        __builtin_amdgcn_s_setprio(0);

        // online softmax; S row = l4*4 + j (wave's 16 rows), col = ct*16 + l15
        // l-sum deferred: lrow[j] holds this lane's partial, reduced in epilogue.
        #pragma unroll
        for (int j = 0; j < 4; ++j) {
            float tm = fmaxf(sacc[0][j], sacc[1][j]);
            tm = fmaxf(tm, __shfl_xor(tm, 1, 64));
            tm = fmaxf(tm, __shfl_xor(tm, 2, 64));
            tm = fmaxf(tm, __shfl_xor(tm, 4, 64));
            tm = fmaxf(tm, __shfl_xor(tm, 8, 64));
            float mold = mrow[j];
            float mnew = fmaxf(mold, tm);
            mrow[j] = mnew;
            float p0 = __expf(sacc[0][j] - mnew);
            float p1 = __expf(sacc[1][j] - mnew);
            if (__all(mnew == mold)) {
                lrow[j] += p0 + p1;
            } else {
                float alpha = __expf(mold - mnew);   // 0 on first tile
                lrow[j] = lrow[j] * alpha + (p0 + p1);
                #pragma unroll
                for (int ct = 0; ct < 17; ++ct)
                    oacc[ct][j] *= alpha;
            }
            int prow = l4*4 + j;
            int swz = (prow >> 1) & 3;
            int base = (w*MW + prow) * 32;
            pb_s[base + ((((l15 >> 3)    ) ^ swz) << 3) + l7] = f2bf(p0);
            pb_s[base + ((((l15 >> 3) + 2) ^ swz) << 3) + l7] = f2bf(p1);
        }

        // PV: O += P(16x32) @ V(32x272)
        {
            bf16x8 pa = *(const bf16x8*)((const char*)pb_s + pbr);
            __builtin_amdgcn_s_setprio(1);
            #pragma unroll
            for (int ct = 0; ct < 17; ++ct) {
                bf16x8 bv = *(const bf16x8*)((const char*)vt_s + vbase + ct*1024);
                oacc[ct] = __builtin_amdgcn_mfma_f32_16x16x32_bf16(pa, bv, oacc[ct], 0, 0, 0);
            }
            __builtin_amdgcn_s_setprio(0);
        }
        __syncthreads();   // all waves done reading; next iter's DMA may write
    }

    // epilogue: reduce deferred l over the 16 lanes of each row, then scatter
    const size_t mv_total = (size_t)HH * NN * 256;
    #pragma unroll
    for (int j = 0; j < 4; ++j) {
        float l = lrow[j];
        l += __shfl_xor(l, 1, 64);
        l += __shfl_xor(l, 2, 64);
        l += __shfl_xor(l, 4, 64);
        l += __shfl_xor(l, 8, 64);
        float inv = 1.0f / l;
        int q = q0 + w*MW + l4*4 + j;
        float* po = out + ((size_t)h*NN + q) * 256 + l15;
        #pragma unroll
        for (int ct = 0; ct < 16; ++ct)
            po[ct*16] = oacc[ct][j] * inv;
        out[mv_total + ((size_t)h*NN + q)*16 + l15] = oacc[16][j] * inv;
    }
}

extern "C" void kernel_launch(void* const* d_in, const int* in_sizes, int n_in,
                              void* d_out, int out_size, void* d_ws, size_t ws_size,
                              hipStream_t stream)
{
    const float* q_mv = (const float*)d_in[0];
    const float* k_mv = (const float*)d_in[1];
    const float* v_mv = (const float*)d_in[2];
    const float* q_s  = (const float*)d_in[3];
    const float* k_s  = (const float*)d_in[4];
    const float* v_s  = (const float*)d_in[5];
    const float* basis_q = (const float*)d_in[6];
    const float* basis_k = (const float*)d_in[7];
    float* out = (float*)d_out;

    unsigned short* qf  = (unsigned short*)d_ws;                  // [8][4096][320]
    unsigned short* kf  = qf  + (size_t)HH*NN*DQK;                // [8][4096][320]
    unsigned short* qml = kf  + (size_t)HH*NN*DQK;                // [8][4096][128]
    unsigned short* kml = qml + (size_t)HH*NN*DML;                // [8][4096][128]
    unsigned short* vt  = kml + (size_t)HH*NN*DML;                // [8][272][4096]
    // total ws use: 76,546,048 bytes

    const float qscale = 0.05735393346764042f;  // 1/sqrt(304); k-rescale is exactly 1

    feat_kernel<<<dim3(1024), dim3(256), 0, stream>>>(q_mv, q_s, basis_q, qscale, qf, qml);
    feat_kernel<<<dim3(1024), dim3(256), 0, stream>>>(k_mv, k_s, basis_k, 1.0f, kf, kml);
    vtrans_kernel<<<dim3(512), dim3(256), 0, stream>>>(v_mv, v_s, vt);
    attn_kernel<<<dim3(512), dim3(256), 0, stream>>>(qf, kf, qml, kml, vt, out);
}

// Round 7
// 314.980 us; speedup vs baseline: 9.2045x; 2.5477x over previous
//
#include <hip/hip_runtime.h>
#include <math.h>

typedef short bf16x8 __attribute__((ext_vector_type(8)));
typedef float f32x4 __attribute__((ext_vector_type(4)));

#define HH 8
#define NN 4096
#define DIP 256   // ip(240) + s(16), no pad
#define DDX 256   // qdx: [hi|hi | mid|lo | mid32-47+16z | hi32-47+16z]
#define DKM 192   // kmx: [mid | lo | hi | hi]
#define DV 272
#define BN 32
#define NT (NN/BN)

typedef const __attribute__((address_space(1))) unsigned int* gp_t;
typedef __attribute__((address_space(3))) unsigned int* lp_t;
__device__ __forceinline__ void gload16(const void* g, void* l) {
    __builtin_amdgcn_global_load_lds((gp_t)g, (lp_t)l, 16, 0, 0);
}

__device__ __forceinline__ unsigned short f2bf(float f) {
    unsigned int u = __float_as_uint(f);
    u = (u + 0x7fffu + ((u >> 16) & 1u)) >> 16;   // RNE
    return (unsigned short)u;
}
__device__ __forceinline__ float bf2f(unsigned short h) {
    return __uint_as_float(((unsigned int)h) << 16);
}

// ---- stage 1a: features. fip[256] = ip+s. fdx: Q-mode 256 cols / K-mode 192 cols ----
__global__ void feat_kernel(const float* __restrict__ mv,
                            const float* __restrict__ sv,
                            const float* __restrict__ basis,
                            float scale, int qmode,
                            unsigned short* __restrict__ fip,
                            unsigned short* __restrict__ fdx)
{
    __shared__ float sb[150];
    int t = threadIdx.x;
    if (t < 150) sb[t] = basis[t];
    __syncthreads();
    int row = blockIdx.x * 32 + (t >> 3);   // (h*4096+n)
    int c = t & 7;
    const float* m = mv + (size_t)row * 256 + c * 32;
    float f[32];
    #pragma unroll
    for (int i = 0; i < 8; ++i) {
        float4 v = ((const float4*)m)[i];
        f[i*4+0] = v.x; f[i*4+1] = v.y; f[i*4+2] = v.z; f[i*4+3] = v.w;
    }
    unsigned short* ip = fip + (size_t)row * DIP;
    unsigned short* dx = fdx + (size_t)row * (qmode ? DDX : DKM);
    #pragma unroll
    for (int j = 0; j < 30; ++j)
        ip[c*30 + j] = f2bf(f[1+j] * scale);
    if (c < 2) {
        #pragma unroll
        for (int i = 0; i < 8; ++i)
            ip[240 + c*8 + i] = f2bf(sv[(size_t)row*16 + c*8 + i] * scale);
    }
    float nn = 1.0f / sqrtf(f[5]*f[5] + 0.001f);
    float tn[5];
    #pragma unroll
    for (int x = 0; x < 5; ++x) tn[x] = f[1+x] * nn;
    #pragma unroll
    for (int z = 0; z < 6; ++z) {
        float acc = 0.f;
        #pragma unroll
        for (int x = 0; x < 5; ++x) {
            #pragma unroll
            for (int y = 0; y < 5; ++y)
                acc = fmaf(sb[(x*5+y)*6 + z] * tn[x], tn[y], acc);
        }
        acc *= scale;
        unsigned short hi = f2bf(acc);
        float r1 = acc - bf2f(hi);
        unsigned short mi = f2bf(r1);
        float r2 = r1 - bf2f(mi);
        unsigned short lo = f2bf(r2);
        int cz = c*6 + z;
        if (qmode) {
            dx[cz]      = hi;  dx[48 + cz]  = hi;
            dx[96 + cz] = mi;  dx[144 + cz] = lo;
            if (cz < 16) { dx[208 + cz] = 0; dx[240 + cz] = 0; }
            if (cz >= 32) { dx[160 + cz] = mi; dx[192 + cz] = hi; }  // 192+(cz-32), 224+(cz-32)
        } else {
            dx[cz]      = mi;  dx[48 + cz]  = lo;
            dx[96 + cz] = hi;  dx[144 + cz] = hi;
        }
    }
}

// ---- stage 1b: V -> transposed bf16 [8][272][4096] ----
__global__ void vtrans_kernel(const float* __restrict__ vmv,
                              const float* __restrict__ vs,
                              unsigned short* __restrict__ dst)
{
    __shared__ unsigned short tile[64][DV];
    int blk = blockIdx.x;
    int h = blk >> 6;
    int n0 = (blk & 63) << 6;
    int t = threadIdx.x;
    #pragma unroll
    for (int it = 0; it < 16; ++it) {
        int v = t + it*256;
        int r = v >> 6;
        int sg = v & 63;
        float4 x = *(const float4*)(vmv + ((size_t)(h*NN + n0 + r))*256 + sg*4);
        tile[r][sg*4+0] = f2bf(x.x);
        tile[r][sg*4+1] = f2bf(x.y);
        tile[r][sg*4+2] = f2bf(x.z);
        tile[r][sg*4+3] = f2bf(x.w);
    }
    #pragma unroll
    for (int it = 0; it < 4; ++it) {
        int v = t + it*256;
        int r = v >> 4;
        int si = v & 15;
        tile[r][256 + si] = f2bf(vs[((size_t)(h*NN + n0 + r))*16 + si]);
    }
    __syncthreads();
    #pragma unroll
    for (int it = 0; it < 17; ++it) {
        int v = t + it*256;
        int dd = v >> 4;
        int sg = v & 15;
        ushort4 o;
        o.x = tile[sg*4+0][dd];
        o.y = tile[sg*4+1][dd];
        o.z = tile[sg*4+2][dd];
        o.w = tile[sg*4+3][dd];
        *(ushort4*)(dst + ((size_t)(h*DV + dd))*NN + n0 + sg*4) = o;
    }
}

// ---- stage 2: flash attention, counted-vmcnt pipeline, 2 blocks/CU ----
__global__ __launch_bounds__(256, 2)
void attn_kernel(const unsigned short* __restrict__ Qip,
                 const unsigned short* __restrict__ Qdx,
                 const unsigned short* __restrict__ Kip,
                 const unsigned short* __restrict__ Kmx,
                 const unsigned short* __restrict__ Vt,
                 float* __restrict__ out)
{
    // LDS (ush): [0,16384) kt 2x8192 | [16384,28672) kmx 2x6144 | [28672,37376) vt | [37376,39424) pb
    __shared__ __align__(128) unsigned short smem[39424];   // 78848 B

    int blk = blockIdx.x;
    int sbk = ((blk & 7) << 6) | (blk >> 3);   // grid 512, bijective XCD swizzle
    int h = sbk >> 6;
    int q0 = (sbk & 63) * 64;
    int tid = threadIdx.x;
    int w = tid >> 6;
    int lane = tid & 63;
    int l15 = lane & 15;
    int l4 = lane >> 4;
    int l7l = l15 & 3;
    int l7h = (l15 >> 2) & 1;

    // Q fragments (B-operand: col=q=l15, dims l4*8..)
    const unsigned short* qipr = Qip + (size_t)(h*NN + q0 + w*16 + l15) * DIP + l4*8;
    const unsigned short* qdxr = Qdx + (size_t)(h*NN + q0 + w*16 + l15) * DDX + l4*8;
    bf16x8 qip[8], qdx[8];
    #pragma unroll
    for (int ks = 0; ks < 8; ++ks) qip[ks] = *(const bf16x8*)(qipr + ks*32);
    #pragma unroll
    for (int ks = 0; ks < 8; ++ks) qdx[ks] = *(const bf16x8*)(qdxr + ks*32);

    // LDS read bases (bytes)
    int cl16 = (l4 ^ l7l) * 16;
    int kbE = l15*512 + cl16 + l7h*64;
    int kbO = l15*512 + cl16 + 64 - l7h*64;
    int mA  = l15*384 + cl16 + l7h*64;
    int mB  = l15*384 + cl16 + 64 - l7h*64;
    int vbs = 57344 + (l15>>1)*128 + (((((l15&1)<<2) | l4) ^ (l15>>1)) << 4);
    int pbR = 74752 + w*1024 + l15*64;
    int pSeg0 = pbR + ((((l4>>1)    ) ^ l7l) << 4) + (l4&1)*8;
    int pSeg1 = pbR + ((((l4>>1) + 2) ^ l7l) << 4) + (l4&1)*8;
    int pRd   = pbR + ((l4 ^ l7l) << 4);

    // DMA source offsets (ush), loop-invariant
    int kto0, kto1, kto2, kto3, kmo0, kmo1, kmo2, vto0, vto1, vto2, vto3, vto4;
#define KTFL(SLOT, DST) { int r_ = (SLOT) >> 5, fp_ = (SLOT) & 31; \
    int fl_ = (fp_ & 24) | ((((fp_>>2)&1) ^ ((r_>>2)&1)) << 2) | ((fp_&3) ^ (r_&3)); \
    DST = r_*DIP + fl_*8; }
    KTFL(tid,     kto0) KTFL(tid+256, kto1) KTFL(tid+512, kto2) KTFL(tid+768, kto3)
#define KMFL(SLOT, DST) { int r_ = (SLOT)/24, fp_ = (SLOT)%24; \
    int g_ = fp_>>3, po_ = fp_&7; \
    int pl_ = ((((po_>>2)&1) ^ ((r_>>2)&1)) << 2) | ((po_&3) ^ (r_&3)); \
    DST = r_*DKM + (g_*8 + pl_)*8; }
    KMFL(tid,     kmo0) KMFL(tid+256, kmo1) KMFL(tid+512, kmo2)
#define VTF(SLOT, DST) { int ch_ = (SLOT) >> 3, ws_ = (SLOT) & 7; int lw_ = ws_ ^ (ch_&7); \
    DST = (ch_*2 + (lw_>>2))*NN + (lw_&3)*8; }
    VTF(tid,      vto0) VTF(tid+256,  vto1) VTF(tid+512, vto2)
    VTF(tid+768,  vto3) VTF(tid+1024, vto4)
#undef KTFL
#undef KMFL
#undef VTF

    const unsigned short* kiph = Kip + (size_t)h*NN*DIP;
    const unsigned short* kmxh = Kmx + (size_t)h*NN*DKM;
    const unsigned short* vh   = Vt  + (size_t)h*DV*NN;

    f32x4 zero = {0.f, 0.f, 0.f, 0.f};
    f32x4 oacc[17];
    #pragma unroll
    for (int ct = 0; ct < 17; ++ct) oacc[ct] = zero;
    float mreg = -__builtin_inff();
    float lreg = 0.f;

#define ISSUE_KTMX(TILE, BUF) do { \
    const unsigned short* ks_ = kiph + (size_t)(TILE)*BN*DIP; \
    unsigned short* d0_ = smem + (BUF)*8192 + tid*8; \
    gload16(ks_ + kto0, d0_); \
    gload16(ks_ + kto1, d0_ + 2048); \
    gload16(ks_ + kto2, d0_ + 4096); \
    gload16(ks_ + kto3, d0_ + 6144); \
    const unsigned short* ms_ = kmxh + (size_t)(TILE)*BN*DKM; \
    unsigned short* d1_ = smem + 16384 + (BUF)*6144 + tid*8; \
    gload16(ms_ + kmo0, d1_); \
    gload16(ms_ + kmo1, d1_ + 2048); \
    gload16(ms_ + kmo2, d1_ + 4096); \
} while (0)

#define ISSUE_V(TILE) do { \
    const unsigned short* vs_ = vh + (TILE)*BN; \
    unsigned short* d2_ = smem + 28672 + tid*8; \
    gload16(vs_ + vto0, d2_); \
    gload16(vs_ + vto1, d2_ + 2048); \
    gload16(vs_ + vto2, d2_ + 4096); \
    gload16(vs_ + vto3, d2_ + 6144); \
    if (tid < 64) gload16(vs_ + vto4, d2_ + 8192); \
} while (0)

    ISSUE_KTMX(0, 0);
    int cur = 0;
    #pragma unroll 1
    for (int t = 0; t < NT; ++t) {
        ISSUE_V(t);                     // safe: post-PV barrier of t-1 passed
        // wait KTMX(t) done (V still in flight); per-wave V count {5,4,4,4}
        if (w == 0) asm volatile("s_waitcnt vmcnt(5)" ::: "memory");
        else        asm volatile("s_waitcnt vmcnt(4)" ::: "memory");
        __builtin_amdgcn_sched_barrier(0);
        __builtin_amdgcn_s_barrier();
        __builtin_amdgcn_sched_barrier(0);
        if (t < NT-1) ISSUE_KTMX(t+1, cur^1);   // flies across all of compute(t)

        const char* ktb = (const char*)smem + cur*16384;
        const char* kmb = (const char*)smem + 32768 + cur*12288;
        f32x4 sacc[2];
        sacc[0] = zero; sacc[1] = zero;
        __builtin_amdgcn_s_setprio(1);
        #pragma unroll
        for (int ks = 0; ks < 8; ++ks) {     // ip+s dims, swapped: mfma(K, Q)
            int off = (ks & 1) ? (kbO + (ks-1)*64) : (kbE + ks*64);
            bf16x8 a0 = *(const bf16x8*)(ktb + off);
            bf16x8 a1 = *(const bf16x8*)(ktb + off + 8192);
            sacc[0] = __builtin_amdgcn_mfma_f32_16x16x32_bf16(a0, qip[ks], sacc[0], 0, 0, 0);
            sacc[1] = __builtin_amdgcn_mfma_f32_16x16x32_bf16(a1, qip[ks], sacc[1], 0, 0, 0);
        }
        #pragma unroll
        for (int ct = 0; ct < 2; ++ct) {     // dist split-precision, dup-block scheme
            const char* kk = kmb + ct*6144;
            bf16x8 ka0 = *(const bf16x8*)(kk + mA);
            bf16x8 ka1 = *(const bf16x8*)(kk + mB);
            bf16x8 ka2 = *(const bf16x8*)(kk + mA + 128);
            bf16x8 kb0 = *(const bf16x8*)(kk + mB + 128);
            bf16x8 kb1 = *(const bf16x8*)(kk + mA + 256);
            bf16x8 kb2 = *(const bf16x8*)(kk + mB + 256);
            f32x4 a = sacc[ct];
            a = __builtin_amdgcn_mfma_f32_16x16x32_bf16(ka0, qdx[0], a, 0, 0, 0); // qh.km head
            a = __builtin_amdgcn_mfma_f32_16x16x32_bf16(ka1, qdx[1], a, 0, 0, 0); // qh.km tail + qh.kl head
            a = __builtin_amdgcn_mfma_f32_16x16x32_bf16(ka2, qdx[2], a, 0, 0, 0); // qh.kl tail
            a = __builtin_amdgcn_mfma_f32_16x16x32_bf16(kb0, qdx[3], a, 0, 0, 0); // qm.kh head
            a = __builtin_amdgcn_mfma_f32_16x16x32_bf16(kb1, qdx[4], a, 0, 0, 0); // qm.kh tail + ql.kh head
            a = __builtin_amdgcn_mfma_f32_16x16x32_bf16(kb2, qdx[5], a, 0, 0, 0); // ql.kh tail
            a = __builtin_amdgcn_mfma_f32_16x16x32_bf16(ka0, qdx[3], a, 0, 0, 0); // qm.km head
            a = __builtin_amdgcn_mfma_f32_16x16x32_bf16(ka1, qdx[6], a, 0, 0, 0); // qm.km tail (z-kill)
            a = __builtin_amdgcn_mfma_f32_16x16x32_bf16(kb0, qdx[0], a, 0, 0, 0); // qh.kh head
            a = __builtin_amdgcn_mfma_f32_16x16x32_bf16(kb1, qdx[7], a, 0, 0, 0); // qh.kh tail (z-kill)
            sacc[ct] = a;
        }
        __builtin_amdgcn_s_setprio(0);

        // online softmax, per-lane q=l15; defer-max THR=8
        float pm = fmaxf(fmaxf(fmaxf(sacc[0][0], sacc[0][1]), fmaxf(sacc[0][2], sacc[0][3])),
                         fmaxf(fmaxf(sacc[1][0], sacc[1][1]), fmaxf(sacc[1][2], sacc[1][3])));
        pm = fmaxf(pm, __shfl_xor(pm, 16, 64));
        pm = fmaxf(pm, __shfl_xor(pm, 32, 64));
        if (!__all(pm <= mreg + 8.0f)) {
            float mnew = fmaxf(mreg, pm);
            float al = __expf(mreg - mnew);      // 0 on first tile
            mreg = mnew;
            lreg *= al;
            float a0 = __shfl(al, l4*4+0, 64);
            float a1 = __shfl(al, l4*4+1, 64);
            float a2 = __shfl(al, l4*4+2, 64);
            float a3 = __shfl(al, l4*4+3, 64);
            #pragma unroll
            for (int ct = 0; ct < 17; ++ct) {
                oacc[ct][0] *= a0; oacc[ct][1] *= a1;
                oacc[ct][2] *= a2; oacc[ct][3] *= a3;
            }
        }
        float p0 = __expf(sacc[0][0] - mreg), p1 = __expf(sacc[0][1] - mreg);
        float p2 = __expf(sacc[0][2] - mreg), p3 = __expf(sacc[0][3] - mreg);
        float p4 = __expf(sacc[1][0] - mreg), p5 = __expf(sacc[1][1] - mreg);
        float p6 = __expf(sacc[1][2] - mreg), p7 = __expf(sacc[1][3] - mreg);
        lreg += ((p0 + p1) + (p2 + p3)) + ((p4 + p5) + (p6 + p7));
        unsigned r01, r23, r45, r67;
        asm("v_cvt_pk_bf16_f32 %0, %1, %2" : "=v"(r01) : "v"(p0), "v"(p1));
        asm("v_cvt_pk_bf16_f32 %0, %1, %2" : "=v"(r23) : "v"(p2), "v"(p3));
        asm("v_cvt_pk_bf16_f32 %0, %1, %2" : "=v"(r45) : "v"(p4), "v"(p5));
        asm("v_cvt_pk_bf16_f32 %0, %1, %2" : "=v"(r67) : "v"(p6), "v"(p7));
        {
            char* pbp = (char*)smem;
            *(unsigned*)(pbp + pSeg0 + 0) = r01;
            *(unsigned*)(pbp + pSeg0 + 4) = r23;
            *(unsigned*)(pbp + pSeg1 + 0) = r45;
            *(unsigned*)(pbp + pSeg1 + 4) = r67;
        }

        // wait V(t) done (KTMX(t+1)=7 remain in flight)
        if (t < NT-1) asm volatile("s_waitcnt vmcnt(7)" ::: "memory");
        else          asm volatile("s_waitcnt vmcnt(0)" ::: "memory");
        __builtin_amdgcn_sched_barrier(0);
        __builtin_amdgcn_s_barrier();
        __builtin_amdgcn_sched_barrier(0);

        // PV: O += P(16x32) @ V(32x272)
        {
            bf16x8 pa = *(const bf16x8*)((const char*)smem + pRd);
            __builtin_amdgcn_s_setprio(1);
            #pragma unroll
            for (int ct = 0; ct < 17; ++ct) {
                bf16x8 bv = *(const bf16x8*)((const char*)smem + vbs + ct*1024);
                oacc[ct] = __builtin_amdgcn_mfma_f32_16x16x32_bf16(pa, bv, oacc[ct], 0, 0, 0);
            }
            __builtin_amdgcn_s_setprio(0);
        }
        __builtin_amdgcn_s_barrier();        // all waves done reading vt_s
        __builtin_amdgcn_sched_barrier(0);
        cur ^= 1;
    }
#undef ISSUE_KTMX
#undef ISSUE_V

    // epilogue: finish deferred l, scatter
    float lf = lreg;
    lf += __shfl_xor(lf, 16, 64);
    lf += __shfl_xor(lf, 32, 64);
    const size_t mv_total = (size_t)HH * NN * 256;
    #pragma unroll
    for (int j = 0; j < 4; ++j) {
        float inv = 1.0f / __shfl(lf, l4*4 + j, 64);
        int q = q0 + w*16 + l4*4 + j;
        float* po = out + ((size_t)h*NN + q) * 256 + l15;
        #pragma unroll
        for (int ct = 0; ct < 16; ++ct)
            po[ct*16] = oacc[ct][j] * inv;
        out[mv_total + ((size_t)h*NN + q)*16 + l15] = oacc[16][j] * inv;
    }
}

extern "C" void kernel_launch(void* const* d_in, const int* in_sizes, int n_in,
                              void* d_out, int out_size, void* d_ws, size_t ws_size,
                              hipStream_t stream)
{
    const float* q_mv = (const float*)d_in[0];
    const float* k_mv = (const float*)d_in[1];
    const float* v_mv = (const float*)d_in[2];
    const float* q_s  = (const float*)d_in[3];
    const float* k_s  = (const float*)d_in[4];
    const float* v_s  = (const float*)d_in[5];
    const float* basis_q = (const float*)d_in[6];
    const float* basis_k = (const float*)d_in[7];
    float* out = (float*)d_out;

    unsigned short* qip = (unsigned short*)d_ws;                 // [8][4096][256]
    unsigned short* qdx = qip + (size_t)HH*NN*DIP;               // [8][4096][256]
    unsigned short* kip = qdx + (size_t)HH*NN*DDX;               // [8][4096][256]
    unsigned short* kmx = kip + (size_t)HH*NN*DIP;               // [8][4096][192]
    unsigned short* vt  = kmx + (size_t)HH*NN*DKM;               // [8][272][4096]
    // total ws use: 80,740,352 bytes

    const float qscale = 0.05735393346764042f;  // 1/sqrt(304); k-rescale is exactly 1

    feat_kernel<<<dim3(1024), dim3(256), 0, stream>>>(q_mv, q_s, basis_q, qscale, 1, qip, qdx);
    feat_kernel<<<dim3(1024), dim3(256), 0, stream>>>(k_mv, k_s, basis_k, 1.0f,   0, kip, kmx);
    vtrans_kernel<<<dim3(512), dim3(256), 0, stream>>>(v_mv, v_s, vt);
    attn_kernel<<<dim3(512), dim3(256), 0, stream>>>(qip, qdx, kip, kmx, vt, out);
}